// Round 15
// baseline (534.158 us; speedup 1.0000x reference)
//
#include <hip/hip_runtime.h>
#include <math.h>

#define PCHUNK 2048
#define CAP 16384   // slack capacity per bucket (mean 12288, sigma ~110: +37 sigma)

// ---------------- wave helpers ----------------
__device__ inline float wave_sum(float v) {
#pragma unroll
    for (int off = 32; off > 0; off >>= 1)
        v += __shfl_xor(v, off, 64);
    return v;
}

// ---------------- bucketed CSR build (fused across 3 graphs via blockIdx.y) ----
// edata entries packed: src | ((dst & 1023) << 20)  (src < 2^20, local idx 10b)
// Slack layout: bucket b of graph g occupies edata[(g*NBUC+b)*CAP ...]; the
// partition needs no precomputed bases (edges read once).

__global__ void k_part(const int* __restrict__ e0, const int* __restrict__ e1,
                       const int* __restrict__ e2, int* __restrict__ bcur,
                       int* __restrict__ edata, int E, int NBUC) {
    int g = blockIdx.y;
    const int* ei = (g == 0) ? e0 : (g == 1) ? e1 : e2;
    const int* src = ei;
    const int* dst = ei + E;
    int* bc = bcur + g * 128;
    int* ed = edata + (size_t)g * NBUC * CAP;

    __shared__ int hist[128];
    __shared__ int wcur[128];
    int t = threadIdx.x;
    if (t < 128) hist[t] = 0;
    __syncthreads();

    int ebase = blockIdx.x * PCHUNK;
    int dreg[8];
    bool have[8];
#pragma unroll
    for (int r = 0; r < 8; ++r) {
        int e = ebase + r * 256 + t;
        have[r] = (e < E);
        dreg[r] = have[r] ? dst[e] : 0;
        if (have[r]) atomicAdd(&hist[dreg[r] >> 10], 1);
    }
    __syncthreads();
    if (t < NBUC) {
        int h = hist[t];
        int base = (h > 0) ? atomicAdd(&bc[t], h) : 0;
        wcur[t] = t * CAP + base;
    }
    __syncthreads();
#pragma unroll
    for (int r = 0; r < 8; ++r) {
        if (have[r]) {
            int e = ebase + r * 256 + t;
            int b = dreg[r] >> 10;
            int pos = atomicAdd(&wcur[b], 1);
            if (pos < (b + 1) * CAP)               // safety guard (never fires)
                ed[pos] = src[e] | ((dreg[r] & 1023) << 20);
        }
    }
}

// tiny scan of final bucket cursors -> boff; also offs[N] = E.
__global__ void k_bscan(const int* __restrict__ bcur, int* __restrict__ boff,
                        int* __restrict__ offs, int N, int E, int NBUC) {
    int t = threadIdx.x;
    if (t < 3) {
        const int* c = bcur + t * 128;
        int* bo = boff + t * (NBUC + 1);
        int acc = 0;
        for (int b = 0; b < NBUC; ++b) { bo[b] = acc; acc += c[b]; }
        bo[NBUC] = acc;                       // == E
        offs[(size_t)t * (N + 1) + N] = E;
    }
}

// flag3 marking + (block 0) wa[i] = sum_j W[i][j]*a[j] hoisted out of k_score
__global__ void k_flag3w(const int* __restrict__ user, const int* __restrict__ item,
                         int* __restrict__ flag3, const float* __restrict__ W,
                         const float* __restrict__ a, float* __restrict__ wa, int B) {
    int b = blockIdx.x * blockDim.x + threadIdx.x;
    if (b < B) {
        flag3[user[b]] = 1;
        flag3[item[b]] = 1;
    }
    if (blockIdx.x == 0 && threadIdx.x < 64) {
        int i = threadIdx.x;
        float acc = 0.0f;
#pragma unroll
        for (int j = 0; j < 64; ++j) acc += W[i * 64 + j] * a[j];
        wa[i] = acc;
    }
}

// Phase 2: one workgroup per bucket. LDS histogram of the 1024-node slice gives
// degrees (-> dinv), LDS scan gives node offsets (-> offs), counts become LDS
// cursors for the perm scatter. Fused flag2 marking: while scattering we hold
// (src, dst); if flag3[dst], mark flag2[g][src].
__global__ void k_bucket2(const int* __restrict__ edata, const int* __restrict__ bcur,
                          const int* __restrict__ boff, const int* __restrict__ flag3,
                          int* __restrict__ flag2, int* __restrict__ offs,
                          float* __restrict__ dinv, int* __restrict__ perm,
                          int N, int E, int NBUC) {
    int g = blockIdx.y;
    int b = blockIdx.x;
    const int* ed = edata + ((size_t)g * NBUC + b) * CAP;
    int cnt = bcur[g * 128 + b];
    int base = boff[g * (NBUC + 1) + b];
    int* of = offs + (size_t)g * (N + 1);
    float* dv = dinv + (size_t)g * N;
    int* pm = perm + (size_t)g * E;
    int* f2 = flag2 + (size_t)g * N;

    __shared__ int lcnt[1024];
    __shared__ int part[256];
    int t = threadIdx.x;
    int nbase = b << 10;
    for (int i = t; i < 1024; i += 256) lcnt[i] = 0;
    __syncthreads();

    for (int j = t; j < cnt; j += 256)
        atomicAdd(&lcnt[((unsigned)ed[j]) >> 20], 1);
    __syncthreads();

    int i4 = t << 2;
    int c0 = lcnt[i4], c1 = lcnt[i4 + 1], c2 = lcnt[i4 + 2], c3 = lcnt[i4 + 3];
    int tot = c0 + c1 + c2 + c3;
    part[t] = tot;
    __syncthreads();
#pragma unroll
    for (int d = 1; d < 256; d <<= 1) {
        int v = (t >= d) ? part[t - d] : 0;
        __syncthreads();
        part[t] += v;
        __syncthreads();
    }
    int excl = part[t] - tot;
    int cc[4] = {c0, c1, c2, c3};
    int pp[4] = {excl, excl + c0, excl + c0 + c1, excl + c0 + c1 + c2};
#pragma unroll
    for (int k = 0; k < 4; ++k) {
        int n = nbase + i4 + k;
        if (n < N) {
            of[n] = base + pp[k];
            dv[n] = (cc[k] > 0) ? (float)(1.0 / sqrt((double)cc[k])) : 0.0f;
        }
        lcnt[i4 + k] = base + pp[k];
    }
    __syncthreads();
    for (int j = t; j < cnt; j += 256) {
        int v = ed[j];
        int li = ((unsigned)v) >> 20;
        int s = v & 0xFFFFF;
        int pos = atomicAdd(&lcnt[li], 1);
        pm[pos] = s;
        if (flag3[nbase + li]) f2[s] = 1;      // fused mark2 (idempotent race OK)
    }
}

// compact flag arrays into dense lists (order irrelevant)
__global__ void k_lists(const int* __restrict__ flag2, const int* __restrict__ flag3,
                        int* __restrict__ list2, int* __restrict__ list3,
                        int* __restrict__ cnts, int N) {
    int g = blockIdx.y;
    int n = blockIdx.x * blockDim.x + threadIdx.x;
    if (n >= N) return;
    if (flag2[(size_t)g * N + n]) {
        int p = atomicAdd(&cnts[g], 1);
        list2[(size_t)g * N + p] = n;
    }
    if (g == 0 && flag3[n]) {
        int p = atomicAdd(&cnts[3], 1);
        list3[p] = n;
    }
}

// ---------------- SpMM gather (round-12 proven form: direct broadcast loads,
// unroll 4, no launch_bounds; round-13's shfl-prefetch variant regressed) ------

// Layer-1: full pass, fused across the 3 graphs (blockIdx.y = g); reads emb via x.
__global__ void k_gather1(const float* __restrict__ emb, const int* __restrict__ xmap,
                          const int* __restrict__ perm, const int* __restrict__ offs,
                          const float* __restrict__ dinv,
                          float* __restrict__ o0, float* __restrict__ o1,
                          float* __restrict__ o2, int N, int E) {
    int g = blockIdx.y;
    const int* pg = perm + (size_t)g * E;
    const int* og = offs + (size_t)g * (N + 1);
    const float* dg = dinv + (size_t)g * N;
    float* out = (g == 0) ? o0 : (g == 1) ? o1 : o2;

    int n = blockIdx.x * (blockDim.x >> 4) + (threadIdx.x >> 4);
    if (n >= N) return;
    int ql = threadIdx.x & 15;
    int j0 = og[n], j1 = og[n + 1];
    const float4* h4 = (const float4*)emb;
    float ax = 0.f, ay = 0.f, az = 0.f, aw = 0.f;
#pragma unroll 4
    for (int j = j0; j < j1; ++j) {
        int s = pg[j];
        float w = dg[s];
        int row = xmap[s];
        float4 v = h4[(size_t)row * 16 + ql];
        ax += w * v.x; ay += w * v.y; az += w * v.z; aw += w * v.w;
    }
    float wd = dg[n];
    ((float4*)out)[(size_t)n * 16 + ql] = make_float4(ax * wd, ay * wd, az * wd, aw * wd);
}

// list-driven pruned gather: grid-stride over a dense active-node list
__global__ void k_gatherL(const float* __restrict__ hin, const int* __restrict__ list,
                          const int* __restrict__ cntp, const int* __restrict__ pg,
                          const int* __restrict__ og, const float* __restrict__ dg,
                          float* __restrict__ out, int N) {
    int cnt = *cntp;
    int groups = (gridDim.x * blockDim.x) >> 4;
    int gidx = (blockIdx.x * blockDim.x + threadIdx.x) >> 4;
    int ql = threadIdx.x & 15;
    const float4* h4 = (const float4*)hin;
    for (int i = gidx; i < cnt; i += groups) {
        int n = list[i];
        int j0 = og[n], j1 = og[n + 1];
        float ax = 0.f, ay = 0.f, az = 0.f, aw = 0.f;
#pragma unroll 4
        for (int j = j0; j < j1; ++j) {
            int s = pg[j];
            float w = dg[s];
            float4 v = h4[(size_t)s * 16 + ql];
            ax += w * v.x; ay += w * v.y; az += w * v.z; aw += w * v.w;
        }
        float wd = dg[n];
        ((float4*)out)[(size_t)n * 16 + ql] = make_float4(ax * wd, ay * wd, az * wd, aw * wd);
    }
}

// ---------------- epilogue ----------------

__device__ inline float node_val(const float* __restrict__ l0, const float* __restrict__ l1,
                                 const float* __restrict__ l2, size_t base, float w) {
    float e0 = l0[base], e1 = l1[base], e2 = l2[base];
    float s0 = wave_sum(e0 * w);
    float s1 = wave_sum(e1 * w);
    float s2 = wave_sum(e2 * w);
    float m = fmaxf(fmaxf(s0, s1), s2);
    float x0 = expf(s0 - m), x1 = expf(s1 - m), x2 = expf(s2 - m);
    return (x0 * e0 + x1 * e1 + x2 * e2) / (x0 + x1 + x2);
}

__global__ void k_score(const int* __restrict__ user, const int* __restrict__ item,
                        const float* __restrict__ l0, const float* __restrict__ l1,
                        const float* __restrict__ l2, const float* __restrict__ wa,
                        float* __restrict__ out, int B) {
    int lane = threadIdx.x & 63;
    float w = wa[lane];
    int b = blockIdx.x * (blockDim.x >> 6) + (threadIdx.x >> 6);
    if (b >= B) return;
    float nu = node_val(l0, l1, l2, (size_t)user[b] * 64 + lane, w);
    float ni = node_val(l0, l1, l2, (size_t)item[b] * 64 + lane, w);
    float p = wave_sum(nu * ni);
    if (lane == 0) out[b] = p;
}

// ---------------- launch ----------------
extern "C" void kernel_launch(void* const* d_in, const int* in_sizes, int n_in,
                              void* d_out, int out_size, void* d_ws, size_t ws_size,
                              hipStream_t stream) {
    const int* user = (const int*)d_in[0];
    const int* item = (const int*)d_in[1];
    const int* x    = (const int*)d_in[2];
    const int* ei[3] = {(const int*)d_in[3], (const int*)d_in[4], (const int*)d_in[5]};
    const float* emb = (const float*)d_in[6];
    const float* W   = (const float*)d_in[7];
    const float* a   = (const float*)d_in[8];
    float* out = (float*)d_out;

    const int B = in_sizes[0];
    const int N = in_sizes[2];
    const int E = in_sizes[3] / 2;
    const int NBUC = (N + 1023) >> 10;          // 98 for N=100000 (<=128)

    // ---- workspace layout (~123MB, within the proven envelope) ----
    size_t ND = (size_t)N * 64;
    float* fws = (float*)d_ws;
    float* l0   = fws;
    float* l1   = l0 + ND;
    float* l2   = l1 + ND;
    float* t0   = l2 + ND;
    float* dinv = t0 + ND;                      // [3][N]
    float* wa   = dinv + (size_t)3 * N;         // [64]
    int* bcur  = (int*)(wa + 64);               // [3][128] -- memset block start
    int* cnts  = bcur + 3 * 128;                // [128] (uses 4)
    int* flag3 = cnts + 128;                    // [N]
    int* flag2 = flag3 + N;                     // [3][N]   -- memset block end
    int* list3 = flag2 + (size_t)3 * N;         // [N]
    int* list2 = list3 + N;                     // [3][N]
    int* offs  = list2 + (size_t)3 * N;         // [3][N+1]
    int* boff  = offs + (size_t)3 * (N + 1);    // [3][NBUC+1]
    int* perm  = boff + 3 * (NBUC + 1);         // [3][E]
    // edata[3][NBUC][CAP] ints (19.3MB) overlays l1 (25.6MB): dead until after
    // CSR build; all build kernels complete before gather1 writes l1.
    int* edata = (int*)l1;
    float* lbuf[3] = {l0, l1, l2};

    const int pblk = (E + PCHUNK - 1) / PCHUNK;
    const int nblk = (N + 255) / 256;
    const int ngrid = (N + 15) / 16;            // quarter-wave per node

    // one memset covers bcur + cnts + flag3 + flag2
    hipMemsetAsync(bcur, 0, ((size_t)512 + (size_t)4 * N) * sizeof(int), stream);

    k_flag3w<<<(B + 255) / 256, 256, 0, stream>>>(user, item, flag3, W, a, wa, B);
    k_part<<<dim3(pblk, 3), 256, 0, stream>>>(ei[0], ei[1], ei[2], bcur, edata, E, NBUC);
    k_bscan<<<1, 64, 0, stream>>>(bcur, boff, offs, N, E, NBUC);
    k_bucket2<<<dim3(NBUC, 3), 256, 0, stream>>>(edata, bcur, boff, flag3, flag2,
                                                 offs, dinv, perm, N, E, NBUC);
    k_lists<<<dim3(nblk, 3), 256, 0, stream>>>(flag2, flag3, list2, list3, cnts, N);

    // layer 1: full, fused across graphs
    k_gather1<<<dim3(ngrid, 3), 256, 0, stream>>>(emb, x, perm, offs, dinv,
                                                  l0, l1, l2, N, E);

    // layers 2+3: list-driven (dense fill, no flag-test waste)
    for (int g = 0; g < 3; ++g) {
        const int* pg = perm + (size_t)g * E;
        const int* og = offs + (size_t)g * (N + 1);
        const float* dg = dinv + (size_t)g * N;
        k_gatherL<<<1024, 256, 0, stream>>>(lbuf[g], list2 + (size_t)g * N, cnts + g,
                                            pg, og, dg, t0, N);
        k_gatherL<<<1024, 256, 0, stream>>>(t0, list3, cnts + 3,
                                            pg, og, dg, lbuf[g], N);
    }

    k_score<<<(B + 3) / 4, 256, 0, stream>>>(user, item, l0, l1, l2, wa, out, B);
}

// Round 16
// 511.649 us; speedup vs baseline: 1.0440x; 1.0440x over previous
//
#include <hip/hip_runtime.h>
#include <math.h>

#define PCHUNK 2048
#define CAP 16384   // slack capacity per bucket (mean 12288, sigma ~110: +37 sigma)

// ---------------- wave helpers ----------------
__device__ inline float wave_sum(float v) {
#pragma unroll
    for (int off = 32; off > 0; off >>= 1)
        v += __shfl_xor(v, off, 64);
    return v;
}

// ---------------- bucketed CSR build (fused across 3 graphs via blockIdx.y) ----
// edata entries packed: src | ((dst & 1023) << 20)  (src < 2^20, local idx 10b)
// Slack layout: bucket b of graph g occupies edata[(g*NBUC+b)*CAP ...]; the
// partition needs no precomputed bases (edges read once).

__global__ void k_part(const int* __restrict__ e0, const int* __restrict__ e1,
                       const int* __restrict__ e2, int* __restrict__ bcur,
                       int* __restrict__ edata, int E, int NBUC) {
    int g = blockIdx.y;
    const int* ei = (g == 0) ? e0 : (g == 1) ? e1 : e2;
    const int* src = ei;
    const int* dst = ei + E;
    int* bc = bcur + g * 128;
    int* ed = edata + (size_t)g * NBUC * CAP;

    __shared__ int hist[128];
    __shared__ int wcur[128];
    int t = threadIdx.x;
    if (t < 128) hist[t] = 0;
    __syncthreads();

    int ebase = blockIdx.x * PCHUNK;
    int dreg[8];
    bool have[8];
#pragma unroll
    for (int r = 0; r < 8; ++r) {
        int e = ebase + r * 256 + t;
        have[r] = (e < E);
        dreg[r] = have[r] ? dst[e] : 0;
        if (have[r]) atomicAdd(&hist[dreg[r] >> 10], 1);
    }
    __syncthreads();
    if (t < NBUC) {
        int h = hist[t];
        int base = (h > 0) ? atomicAdd(&bc[t], h) : 0;
        wcur[t] = t * CAP + base;
    }
    __syncthreads();
#pragma unroll
    for (int r = 0; r < 8; ++r) {
        if (have[r]) {
            int e = ebase + r * 256 + t;
            int b = dreg[r] >> 10;
            int pos = atomicAdd(&wcur[b], 1);
            if (pos < (b + 1) * CAP)               // safety guard (never fires)
                ed[pos] = src[e] | ((dreg[r] & 1023) << 20);
        }
    }
}

// tiny scan of final bucket cursors -> boff; also offs[N] = E.
__global__ void k_bscan(const int* __restrict__ bcur, int* __restrict__ boff,
                        int* __restrict__ offs, int N, int E, int NBUC) {
    int t = threadIdx.x;
    if (t < 3) {
        const int* c = bcur + t * 128;
        int* bo = boff + t * (NBUC + 1);
        int acc = 0;
        for (int b = 0; b < NBUC; ++b) { bo[b] = acc; acc += c[b]; }
        bo[NBUC] = acc;                       // == E
        offs[(size_t)t * (N + 1) + N] = E;
    }
}

// flag3 marking + (block 0) wa[i] = sum_j W[i][j]*a[j] hoisted out of k_score
__global__ void k_flag3w(const int* __restrict__ user, const int* __restrict__ item,
                         int* __restrict__ flag3, const float* __restrict__ W,
                         const float* __restrict__ a, float* __restrict__ wa, int B) {
    int b = blockIdx.x * blockDim.x + threadIdx.x;
    if (b < B) {
        flag3[user[b]] = 1;
        flag3[item[b]] = 1;
    }
    if (blockIdx.x == 0 && threadIdx.x < 64) {
        int i = threadIdx.x;
        float acc = 0.0f;
#pragma unroll
        for (int j = 0; j < 64; ++j) acc += W[i * 64 + j] * a[j];
        wa[i] = acc;
    }
}

// Phase 2: one workgroup per bucket. LDS histogram of the 1024-node slice gives
// degrees (-> dinv), LDS scan gives node offsets (-> offs), counts become LDS
// cursors for the perm scatter. Fused flag2 marking: while scattering we hold
// (src, dst); if flag3[dst], mark flag2[g][src].
__global__ void k_bucket2(const int* __restrict__ edata, const int* __restrict__ bcur,
                          const int* __restrict__ boff, const int* __restrict__ flag3,
                          int* __restrict__ flag2, int* __restrict__ offs,
                          float* __restrict__ dinv, int* __restrict__ perm,
                          int N, int E, int NBUC) {
    int g = blockIdx.y;
    int b = blockIdx.x;
    const int* ed = edata + ((size_t)g * NBUC + b) * CAP;
    int cnt = bcur[g * 128 + b];
    int base = boff[g * (NBUC + 1) + b];
    int* of = offs + (size_t)g * (N + 1);
    float* dv = dinv + (size_t)g * N;
    int* pm = perm + (size_t)g * E;
    int* f2 = flag2 + (size_t)g * N;

    __shared__ int lcnt[1024];
    __shared__ int part[256];
    int t = threadIdx.x;
    int nbase = b << 10;
    for (int i = t; i < 1024; i += 256) lcnt[i] = 0;
    __syncthreads();

    for (int j = t; j < cnt; j += 256)
        atomicAdd(&lcnt[((unsigned)ed[j]) >> 20], 1);
    __syncthreads();

    int i4 = t << 2;
    int c0 = lcnt[i4], c1 = lcnt[i4 + 1], c2 = lcnt[i4 + 2], c3 = lcnt[i4 + 3];
    int tot = c0 + c1 + c2 + c3;
    part[t] = tot;
    __syncthreads();
#pragma unroll
    for (int d = 1; d < 256; d <<= 1) {
        int v = (t >= d) ? part[t - d] : 0;
        __syncthreads();
        part[t] += v;
        __syncthreads();
    }
    int excl = part[t] - tot;
    int cc[4] = {c0, c1, c2, c3};
    int pp[4] = {excl, excl + c0, excl + c0 + c1, excl + c0 + c1 + c2};
#pragma unroll
    for (int k = 0; k < 4; ++k) {
        int n = nbase + i4 + k;
        if (n < N) {
            of[n] = base + pp[k];
            dv[n] = (cc[k] > 0) ? (float)(1.0 / sqrt((double)cc[k])) : 0.0f;
        }
        lcnt[i4 + k] = base + pp[k];
    }
    __syncthreads();
    for (int j = t; j < cnt; j += 256) {
        int v = ed[j];
        int li = ((unsigned)v) >> 20;
        int s = v & 0xFFFFF;
        int pos = atomicAdd(&lcnt[li], 1);
        pm[pos] = s;
        if (flag3[nbase + li]) f2[s] = 1;      // fused mark2 (idempotent race OK)
    }
}

// compact flag arrays into dense lists (order irrelevant)
__global__ void k_lists(const int* __restrict__ flag2, const int* __restrict__ flag3,
                        int* __restrict__ list2, int* __restrict__ list3,
                        int* __restrict__ cnts, int N) {
    int g = blockIdx.y;
    int n = blockIdx.x * blockDim.x + threadIdx.x;
    if (n >= N) return;
    if (flag2[(size_t)g * N + n]) {
        int p = atomicAdd(&cnts[g], 1);
        list2[(size_t)g * N + p] = n;
    }
    if (g == 0 && flag3[n]) {
        int p = atomicAdd(&cnts[3], 1);
        list3[p] = n;
    }
}

// ---------------- SpMM gather ----------------
// out[n] = dinv[n] * sum_{s in N(n)} dinv[s] * hin[s]
// 16 lanes (quarter-wave) per node; direct broadcast loads, unroll 4 (the
// round-12 proven form; shfl-prefetch (r13) and small-grid list-stride (r15)
// both regressed).

// Layer-1: full pass, fused across the 3 graphs (blockIdx.y = g); reads emb via x.
__global__ void k_gather1(const float* __restrict__ emb, const int* __restrict__ xmap,
                          const int* __restrict__ perm, const int* __restrict__ offs,
                          const float* __restrict__ dinv,
                          float* __restrict__ o0, float* __restrict__ o1,
                          float* __restrict__ o2, int N, int E) {
    int g = blockIdx.y;
    const int* pg = perm + (size_t)g * E;
    const int* og = offs + (size_t)g * (N + 1);
    const float* dg = dinv + (size_t)g * N;
    float* out = (g == 0) ? o0 : (g == 1) ? o1 : o2;

    int n = blockIdx.x * (blockDim.x >> 4) + (threadIdx.x >> 4);
    if (n >= N) return;
    int ql = threadIdx.x & 15;
    int j0 = og[n], j1 = og[n + 1];
    const float4* h4 = (const float4*)emb;
    float ax = 0.f, ay = 0.f, az = 0.f, aw = 0.f;
#pragma unroll 4
    for (int j = j0; j < j1; ++j) {
        int s = pg[j];
        float w = dg[s];
        int row = xmap[s];
        float4 v = h4[(size_t)row * 16 + ql];
        ax += w * v.x; ay += w * v.y; az += w * v.z; aw += w * v.w;
    }
    float wd = dg[n];
    ((float4*)out)[(size_t)n * 16 + ql] = make_float4(ax * wd, ay * wd, az * wd, aw * wd);
}

// list-driven pruned gather, FULL grid: one node per 16-lane group, grid sized
// to the worst-case count on host; groups past the count exit immediately.
// (r15 lesson: a small grid-stride grid halves TLP on a latency-bound pass.)
// Optionally fused across graphs: g = gbase + blockIdx.y; list/cnt strided.
__global__ void k_gatherL(const float* __restrict__ i0, const float* __restrict__ i1,
                          const float* __restrict__ i2, const int* __restrict__ listb,
                          int liststride, const int* __restrict__ cntb, int cntstride,
                          const int* __restrict__ perm, const int* __restrict__ offs,
                          const float* __restrict__ dinv,
                          float* __restrict__ o0, float* __restrict__ o1,
                          float* __restrict__ o2, int N, int E, int gbase) {
    int y = blockIdx.y;
    int g = gbase + y;
    const float* hin = (g == 0) ? i0 : (g == 1) ? i1 : i2;
    float* outp = (g == 0) ? o0 : (g == 1) ? o1 : o2;
    int cnt = cntb[y * cntstride];
    int gidx = blockIdx.x * (blockDim.x >> 4) + (threadIdx.x >> 4);
    if (gidx >= cnt) return;
    int n = listb[(size_t)y * liststride + gidx];
    int ql = threadIdx.x & 15;
    const int* pg = perm + (size_t)g * E;
    const int* og = offs + (size_t)g * (N + 1);
    const float* dg = dinv + (size_t)g * N;
    int j0 = og[n], j1 = og[n + 1];
    const float4* h4 = (const float4*)hin;
    float ax = 0.f, ay = 0.f, az = 0.f, aw = 0.f;
#pragma unroll 4
    for (int j = j0; j < j1; ++j) {
        int s = pg[j];
        float w = dg[s];
        float4 v = h4[(size_t)s * 16 + ql];
        ax += w * v.x; ay += w * v.y; az += w * v.z; aw += w * v.w;
    }
    float wd = dg[n];
    ((float4*)outp)[(size_t)n * 16 + ql] = make_float4(ax * wd, ay * wd, az * wd, aw * wd);
}

// ---------------- epilogue ----------------

__device__ inline float node_val(const float* __restrict__ l0, const float* __restrict__ l1,
                                 const float* __restrict__ l2, size_t base, float w) {
    float e0 = l0[base], e1 = l1[base], e2 = l2[base];
    float s0 = wave_sum(e0 * w);
    float s1 = wave_sum(e1 * w);
    float s2 = wave_sum(e2 * w);
    float m = fmaxf(fmaxf(s0, s1), s2);
    float x0 = expf(s0 - m), x1 = expf(s1 - m), x2 = expf(s2 - m);
    return (x0 * e0 + x1 * e1 + x2 * e2) / (x0 + x1 + x2);
}

__global__ void k_score(const int* __restrict__ user, const int* __restrict__ item,
                        const float* __restrict__ l0, const float* __restrict__ l1,
                        const float* __restrict__ l2, const float* __restrict__ wa,
                        float* __restrict__ out, int B) {
    int lane = threadIdx.x & 63;
    float w = wa[lane];
    int b = blockIdx.x * (blockDim.x >> 6) + (threadIdx.x >> 6);
    if (b >= B) return;
    float nu = node_val(l0, l1, l2, (size_t)user[b] * 64 + lane, w);
    float ni = node_val(l0, l1, l2, (size_t)item[b] * 64 + lane, w);
    float p = wave_sum(nu * ni);
    if (lane == 0) out[b] = p;
}

// ---------------- launch ----------------
extern "C" void kernel_launch(void* const* d_in, const int* in_sizes, int n_in,
                              void* d_out, int out_size, void* d_ws, size_t ws_size,
                              hipStream_t stream) {
    const int* user = (const int*)d_in[0];
    const int* item = (const int*)d_in[1];
    const int* x    = (const int*)d_in[2];
    const int* ei[3] = {(const int*)d_in[3], (const int*)d_in[4], (const int*)d_in[5]};
    const float* emb = (const float*)d_in[6];
    const float* W   = (const float*)d_in[7];
    const float* a   = (const float*)d_in[8];
    float* out = (float*)d_out;

    const int B = in_sizes[0];
    const int N = in_sizes[2];
    const int E = in_sizes[3] / 2;
    const int NBUC = (N + 1023) >> 10;          // 98 for N=100000 (<=128)

    size_t ND = (size_t)N * 64;
    // ints: bcur[384]+cnts[128]+flag3[N]+flag2[3N]+list3[N]+list2[3N]+offs[3(N+1)]
    //       +boff[3(NBUC+1)]+perm[3E]
    size_t nint = 512 + (size_t)8 * N + 3 * (size_t)(N + 1) + 3 * (NBUC + 1) + 3 * (size_t)E;
    size_t needBig = ((size_t)6 * ND + 3 * (size_t)N + 64 + nint) * 4 + 1024;  // 3 tmps
    bool big = (ws_size >= needBig);

    float* fws = (float*)d_ws;
    float* l0   = fws;
    float* l1   = l0 + ND;
    float* l2   = l1 + ND;
    float* t0   = l2 + ND;                      // tmp (x3 big path, x1 small)
    float* t1   = big ? t0 + ND : t0;
    float* t2   = big ? t1 + ND : t0;
    float* dinv = (big ? t2 : t0) + ND;         // [3][N]
    float* wa   = dinv + (size_t)3 * N;         // [64]
    int* bcur  = (int*)(wa + 64);               // [3][128] -- memset block start
    int* cnts  = bcur + 3 * 128;                // [128] (uses 4)
    int* flag3 = cnts + 128;                    // [N]
    int* flag2 = flag3 + N;                     // [3][N]   -- memset block end
    int* list3 = flag2 + (size_t)3 * N;         // [N]
    int* list2 = list3 + N;                     // [3][N]
    int* offs  = list2 + (size_t)3 * N;         // [3][N+1]
    int* boff  = offs + (size_t)3 * (N + 1);    // [3][NBUC+1]
    int* perm  = boff + 3 * (NBUC + 1);         // [3][E]
    // edata[3][NBUC][CAP] ints (19.3MB) overlays l1 (25.6MB): dead until after
    // CSR build; all build kernels complete before gather1 writes l1.
    int* edata = (int*)l1;
    float* lbuf[3] = {l0, l1, l2};

    const int pblk = (E + PCHUNK - 1) / PCHUNK;
    const int nblk = (N + 255) / 256;
    const int ngrid = (N + 15) / 16;            // 16 groups/block, 1 node/group
    const int ngrid3 = (2 * B + 15) / 16;       // layer-3 count <= 2B

    // one memset covers bcur + cnts + flag3 + flag2
    hipMemsetAsync(bcur, 0, ((size_t)512 + (size_t)4 * N) * sizeof(int), stream);

    k_flag3w<<<(B + 255) / 256, 256, 0, stream>>>(user, item, flag3, W, a, wa, B);
    k_part<<<dim3(pblk, 3), 256, 0, stream>>>(ei[0], ei[1], ei[2], bcur, edata, E, NBUC);
    k_bscan<<<1, 64, 0, stream>>>(bcur, boff, offs, N, E, NBUC);
    k_bucket2<<<dim3(NBUC, 3), 256, 0, stream>>>(edata, bcur, boff, flag3, flag2,
                                                 offs, dinv, perm, N, E, NBUC);
    k_lists<<<dim3(nblk, 3), 256, 0, stream>>>(flag2, flag3, list2, list3, cnts, N);

    // layer 1: full, fused across graphs
    k_gather1<<<dim3(ngrid, 3), 256, 0, stream>>>(emb, x, perm, offs, dinv,
                                                  l0, l1, l2, N, E);

    if (big) {
        // layers 2+3 fused across graphs, full grids
        k_gatherL<<<dim3(ngrid, 3), 256, 0, stream>>>(l0, l1, l2, list2, N, cnts, 1,
                                                      perm, offs, dinv,
                                                      t0, t1, t2, N, E, 0);
        k_gatherL<<<dim3(ngrid3, 3), 256, 0, stream>>>(t0, t1, t2, list3, 0, cnts + 3, 0,
                                                       perm, offs, dinv,
                                                       l0, l1, l2, N, E, 0);
    } else {
        for (int g = 0; g < 3; ++g) {
            k_gatherL<<<dim3(ngrid, 1), 256, 0, stream>>>(lbuf[g], lbuf[g], lbuf[g],
                                                          list2 + (size_t)g * N, 0,
                                                          cnts + g, 0,
                                                          perm, offs, dinv,
                                                          t0, t0, t0, N, E, g);
            k_gatherL<<<dim3(ngrid3, 1), 256, 0, stream>>>(t0, t0, t0, list3, 0,
                                                           cnts + 3, 0,
                                                           perm, offs, dinv,
                                                           lbuf[g], lbuf[g], lbuf[g],
                                                           N, E, g);
        }
    }

    k_score<<<(B + 3) / 4, 256, 0, stream>>>(user, item, l0, l1, l2, wa, out, B);
}

// Round 17
// 456.704 us; speedup vs baseline: 1.1696x; 1.1203x over previous
//
#include <hip/hip_runtime.h>
#include <math.h>

#define PCHUNK 2048
#define CAP 16384   // slack capacity per bucket (mean 12288, sigma ~110: +37 sigma)

// ---------------- wave helpers ----------------
__device__ inline float wave_sum(float v) {
#pragma unroll
    for (int off = 32; off > 0; off >>= 1)
        v += __shfl_xor(v, off, 64);
    return v;
}

// ---------------- bucketed CSR build (fused across 3 graphs via blockIdx.y) ----
// edata entries packed: src | ((dst & 1023) << 20)  (src < 2^20, local idx 10b)
// Slack layout: bucket b of graph g occupies edata[(g*NBUC+b)*CAP ...]; the
// partition needs no precomputed bases (edges read once).

__global__ void k_part(const int* __restrict__ e0, const int* __restrict__ e1,
                       const int* __restrict__ e2, int* __restrict__ bcur,
                       int* __restrict__ edata, int E, int NBUC) {
    int g = blockIdx.y;
    const int* ei = (g == 0) ? e0 : (g == 1) ? e1 : e2;
    const int* src = ei;
    const int* dst = ei + E;
    int* bc = bcur + g * 128;
    int* ed = edata + (size_t)g * NBUC * CAP;

    __shared__ int hist[128];
    __shared__ int wcur[128];
    int t = threadIdx.x;
    if (t < 128) hist[t] = 0;
    __syncthreads();

    int ebase = blockIdx.x * PCHUNK;
    int dreg[8];
    bool have[8];
#pragma unroll
    for (int r = 0; r < 8; ++r) {
        int e = ebase + r * 256 + t;
        have[r] = (e < E);
        dreg[r] = have[r] ? dst[e] : 0;
        if (have[r]) atomicAdd(&hist[dreg[r] >> 10], 1);
    }
    __syncthreads();
    if (t < NBUC) {
        int h = hist[t];
        int base = (h > 0) ? atomicAdd(&bc[t], h) : 0;
        wcur[t] = t * CAP + base;
    }
    __syncthreads();
#pragma unroll
    for (int r = 0; r < 8; ++r) {
        if (have[r]) {
            int e = ebase + r * 256 + t;
            int b = dreg[r] >> 10;
            int pos = atomicAdd(&wcur[b], 1);
            if (pos < (b + 1) * CAP)               // safety guard (never fires)
                ed[pos] = src[e] | ((dreg[r] & 1023) << 20);
        }
    }
}

// tiny scan of final bucket cursors -> boff; also offs[N] = E.
__global__ void k_bscan(const int* __restrict__ bcur, int* __restrict__ boff,
                        int* __restrict__ offs, int N, int E, int NBUC) {
    int t = threadIdx.x;
    if (t < 3) {
        const int* c = bcur + t * 128;
        int* bo = boff + t * (NBUC + 1);
        int acc = 0;
        for (int b = 0; b < NBUC; ++b) { bo[b] = acc; acc += c[b]; }
        bo[NBUC] = acc;                       // == E
        offs[(size_t)t * (N + 1) + N] = E;
    }
}

// flag3 marking + (block 0) wa[i] = sum_j W[i][j]*a[j] hoisted out of k_score
__global__ void k_flag3w(const int* __restrict__ user, const int* __restrict__ item,
                         int* __restrict__ flag3, const float* __restrict__ W,
                         const float* __restrict__ a, float* __restrict__ wa, int B) {
    int b = blockIdx.x * blockDim.x + threadIdx.x;
    if (b < B) {
        flag3[user[b]] = 1;
        flag3[item[b]] = 1;
    }
    if (blockIdx.x == 0 && threadIdx.x < 64) {
        int i = threadIdx.x;
        float acc = 0.0f;
#pragma unroll
        for (int j = 0; j < 64; ++j) acc += W[i * 64 + j] * a[j];
        wa[i] = acc;
    }
}

// Phase 2: one workgroup per bucket. LDS histogram of the 1024-node slice gives
// degrees (-> dinv), LDS scan gives node offsets (-> offs), counts become LDS
// cursors for the perm scatter. Fused flag2 marking: while scattering we hold
// (src, dst); if flag3[dst], mark flag2[g][src].
__global__ void k_bucket2(const int* __restrict__ edata, const int* __restrict__ bcur,
                          const int* __restrict__ boff, const int* __restrict__ flag3,
                          int* __restrict__ flag2, int* __restrict__ offs,
                          float* __restrict__ dinv, int* __restrict__ perm,
                          int N, int E, int NBUC) {
    int g = blockIdx.y;
    int b = blockIdx.x;
    const int* ed = edata + ((size_t)g * NBUC + b) * CAP;
    int cnt = bcur[g * 128 + b];
    int base = boff[g * (NBUC + 1) + b];
    int* of = offs + (size_t)g * (N + 1);
    float* dv = dinv + (size_t)g * N;
    int* pm = perm + (size_t)g * E;
    int* f2 = flag2 + (size_t)g * N;

    __shared__ int lcnt[1024];
    __shared__ int part[256];
    int t = threadIdx.x;
    int nbase = b << 10;
    for (int i = t; i < 1024; i += 256) lcnt[i] = 0;
    __syncthreads();

    for (int j = t; j < cnt; j += 256)
        atomicAdd(&lcnt[((unsigned)ed[j]) >> 20], 1);
    __syncthreads();

    int i4 = t << 2;
    int c0 = lcnt[i4], c1 = lcnt[i4 + 1], c2 = lcnt[i4 + 2], c3 = lcnt[i4 + 3];
    int tot = c0 + c1 + c2 + c3;
    part[t] = tot;
    __syncthreads();
#pragma unroll
    for (int d = 1; d < 256; d <<= 1) {
        int v = (t >= d) ? part[t - d] : 0;
        __syncthreads();
        part[t] += v;
        __syncthreads();
    }
    int excl = part[t] - tot;
    int cc[4] = {c0, c1, c2, c3};
    int pp[4] = {excl, excl + c0, excl + c0 + c1, excl + c0 + c1 + c2};
#pragma unroll
    for (int k = 0; k < 4; ++k) {
        int n = nbase + i4 + k;
        if (n < N) {
            of[n] = base + pp[k];
            dv[n] = (cc[k] > 0) ? (float)(1.0 / sqrt((double)cc[k])) : 0.0f;
        }
        lcnt[i4 + k] = base + pp[k];
    }
    __syncthreads();
    for (int j = t; j < cnt; j += 256) {
        int v = ed[j];
        int li = ((unsigned)v) >> 20;
        int s = v & 0xFFFFF;
        int pos = atomicAdd(&lcnt[li], 1);
        pm[pos] = s;
        if (flag3[nbase + li]) f2[s] = 1;      // fused mark2 (idempotent race OK)
    }
}

// ORDERED-CHUNK compaction (r16 lesson: random list order destroys offs/perm
// locality in the gathers). Per 256-node block: LDS inclusive scan of flags,
// ONE atomicAdd reserves a contiguous run, nodes written in order within it.
// Consecutive list entries then come from the same 256-node window.
__global__ void k_lists(const int* __restrict__ flag2, const int* __restrict__ flag3,
                        int* __restrict__ list2, int* __restrict__ list3,
                        int* __restrict__ cnts, int N) {
    int g = blockIdx.y;
    int t = threadIdx.x;
    int n = blockIdx.x * 256 + t;
    __shared__ int s[256];
    __shared__ int base;

    // ---- flag2[g] ----
    int f = (n < N) ? flag2[(size_t)g * N + n] : 0;
    s[t] = f;
    __syncthreads();
#pragma unroll
    for (int d = 1; d < 256; d <<= 1) {
        int v = (t >= d) ? s[t - d] : 0;
        __syncthreads();
        s[t] += v;
        __syncthreads();
    }
    if (t == 0) base = (s[255] > 0) ? atomicAdd(&cnts[g], s[255]) : 0;
    __syncthreads();
    if (f) list2[(size_t)g * N + base + s[t] - 1] = n;
    __syncthreads();

    // ---- flag3 (g==0 only) ----
    if (g == 0) {
        int f3 = (n < N) ? flag3[n] : 0;
        s[t] = f3;
        __syncthreads();
#pragma unroll
        for (int d = 1; d < 256; d <<= 1) {
            int v = (t >= d) ? s[t - d] : 0;
            __syncthreads();
            s[t] += v;
            __syncthreads();
        }
        if (t == 0) base = (s[255] > 0) ? atomicAdd(&cnts[3], s[255]) : 0;
        __syncthreads();
        if (f3) list3[base + s[t] - 1] = n;
    }
}

// ---------------- SpMM gather ----------------
// out[n] = dinv[n] * sum_{s in N(n)} dinv[s] * hin[s]
// 16 lanes (quarter-wave) per node; direct broadcast loads, unroll 4 (the
// round-12 proven form; shfl-prefetch (r13) and small-grid stride (r15) both
// regressed).

// Layer-1: full pass, fused across the 3 graphs (blockIdx.y = g); reads emb via x.
__global__ void k_gather1(const float* __restrict__ emb, const int* __restrict__ xmap,
                          const int* __restrict__ perm, const int* __restrict__ offs,
                          const float* __restrict__ dinv,
                          float* __restrict__ o0, float* __restrict__ o1,
                          float* __restrict__ o2, int N, int E) {
    int g = blockIdx.y;
    const int* pg = perm + (size_t)g * E;
    const int* og = offs + (size_t)g * (N + 1);
    const float* dg = dinv + (size_t)g * N;
    float* out = (g == 0) ? o0 : (g == 1) ? o1 : o2;

    int n = blockIdx.x * (blockDim.x >> 4) + (threadIdx.x >> 4);
    if (n >= N) return;
    int ql = threadIdx.x & 15;
    int j0 = og[n], j1 = og[n + 1];
    const float4* h4 = (const float4*)emb;
    float ax = 0.f, ay = 0.f, az = 0.f, aw = 0.f;
#pragma unroll 4
    for (int j = j0; j < j1; ++j) {
        int s = pg[j];
        float w = dg[s];
        int row = xmap[s];
        float4 v = h4[(size_t)row * 16 + ql];
        ax += w * v.x; ay += w * v.y; az += w * v.z; aw += w * v.w;
    }
    float wd = dg[n];
    ((float4*)out)[(size_t)n * 16 + ql] = make_float4(ax * wd, ay * wd, az * wd, aw * wd);
}

// list-driven pruned gather, FULL grid (one node per 16-lane group; groups past
// the count exit immediately). Optionally fused across graphs via blockIdx.y.
__global__ void k_gatherL(const float* __restrict__ i0, const float* __restrict__ i1,
                          const float* __restrict__ i2, const int* __restrict__ listb,
                          int liststride, const int* __restrict__ cntb, int cntstride,
                          const int* __restrict__ perm, const int* __restrict__ offs,
                          const float* __restrict__ dinv,
                          float* __restrict__ o0, float* __restrict__ o1,
                          float* __restrict__ o2, int N, int E, int gbase) {
    int y = blockIdx.y;
    int g = gbase + y;
    const float* hin = (g == 0) ? i0 : (g == 1) ? i1 : i2;
    float* outp = (g == 0) ? o0 : (g == 1) ? o1 : o2;
    int cnt = cntb[y * cntstride];
    int gidx = blockIdx.x * (blockDim.x >> 4) + (threadIdx.x >> 4);
    if (gidx >= cnt) return;
    int n = listb[(size_t)y * liststride + gidx];
    int ql = threadIdx.x & 15;
    const int* pg = perm + (size_t)g * E;
    const int* og = offs + (size_t)g * (N + 1);
    const float* dg = dinv + (size_t)g * N;
    int j0 = og[n], j1 = og[n + 1];
    const float4* h4 = (const float4*)hin;
    float ax = 0.f, ay = 0.f, az = 0.f, aw = 0.f;
#pragma unroll 4
    for (int j = j0; j < j1; ++j) {
        int s = pg[j];
        float w = dg[s];
        float4 v = h4[(size_t)s * 16 + ql];
        ax += w * v.x; ay += w * v.y; az += w * v.z; aw += w * v.w;
    }
    float wd = dg[n];
    ((float4*)outp)[(size_t)n * 16 + ql] = make_float4(ax * wd, ay * wd, az * wd, aw * wd);
}

// ---------------- epilogue ----------------

__device__ inline float node_val(const float* __restrict__ l0, const float* __restrict__ l1,
                                 const float* __restrict__ l2, size_t base, float w) {
    float e0 = l0[base], e1 = l1[base], e2 = l2[base];
    float s0 = wave_sum(e0 * w);
    float s1 = wave_sum(e1 * w);
    float s2 = wave_sum(e2 * w);
    float m = fmaxf(fmaxf(s0, s1), s2);
    float x0 = expf(s0 - m), x1 = expf(s1 - m), x2 = expf(s2 - m);
    return (x0 * e0 + x1 * e1 + x2 * e2) / (x0 + x1 + x2);
}

__global__ void k_score(const int* __restrict__ user, const int* __restrict__ item,
                        const float* __restrict__ l0, const float* __restrict__ l1,
                        const float* __restrict__ l2, const float* __restrict__ wa,
                        float* __restrict__ out, int B) {
    int lane = threadIdx.x & 63;
    float w = wa[lane];
    int b = blockIdx.x * (blockDim.x >> 6) + (threadIdx.x >> 6);
    if (b >= B) return;
    float nu = node_val(l0, l1, l2, (size_t)user[b] * 64 + lane, w);
    float ni = node_val(l0, l1, l2, (size_t)item[b] * 64 + lane, w);
    float p = wave_sum(nu * ni);
    if (lane == 0) out[b] = p;
}

// ---------------- launch ----------------
extern "C" void kernel_launch(void* const* d_in, const int* in_sizes, int n_in,
                              void* d_out, int out_size, void* d_ws, size_t ws_size,
                              hipStream_t stream) {
    const int* user = (const int*)d_in[0];
    const int* item = (const int*)d_in[1];
    const int* x    = (const int*)d_in[2];
    const int* ei[3] = {(const int*)d_in[3], (const int*)d_in[4], (const int*)d_in[5]};
    const float* emb = (const float*)d_in[6];
    const float* W   = (const float*)d_in[7];
    const float* a   = (const float*)d_in[8];
    float* out = (float*)d_out;

    const int B = in_sizes[0];
    const int N = in_sizes[2];
    const int E = in_sizes[3] / 2;
    const int NBUC = (N + 1023) >> 10;          // 98 for N=100000 (<=128)

    size_t ND = (size_t)N * 64;
    size_t nint = 512 + (size_t)8 * N + 3 * (size_t)(N + 1) + 3 * (NBUC + 1) + 3 * (size_t)E;
    size_t needBig = ((size_t)6 * ND + 3 * (size_t)N + 64 + nint) * 4 + 1024;  // 3 tmps
    bool big = (ws_size >= needBig);

    float* fws = (float*)d_ws;
    float* l0   = fws;
    float* l1   = l0 + ND;
    float* l2   = l1 + ND;
    float* t0   = l2 + ND;                      // tmp (x3 big path, x1 small)
    float* t1   = big ? t0 + ND : t0;
    float* t2   = big ? t1 + ND : t0;
    float* dinv = (big ? t2 : t0) + ND;         // [3][N]
    float* wa   = dinv + (size_t)3 * N;         // [64]
    int* bcur  = (int*)(wa + 64);               // [3][128] -- memset block start
    int* cnts  = bcur + 3 * 128;                // [128] (uses 4)
    int* flag3 = cnts + 128;                    // [N]
    int* flag2 = flag3 + N;                     // [3][N]   -- memset block end
    int* list3 = flag2 + (size_t)3 * N;         // [N]
    int* list2 = list3 + N;                     // [3][N]
    int* offs  = list2 + (size_t)3 * N;         // [3][N+1]
    int* boff  = offs + (size_t)3 * (N + 1);    // [3][NBUC+1]
    int* perm  = boff + 3 * (NBUC + 1);         // [3][E]
    // edata[3][NBUC][CAP] ints (19.3MB) overlays l1 (25.6MB): dead until after
    // CSR build; all build kernels complete before gather1 writes l1.
    int* edata = (int*)l1;
    float* lbuf[3] = {l0, l1, l2};

    const int pblk = (E + PCHUNK - 1) / PCHUNK;
    const int nblk = (N + 255) / 256;
    const int ngrid = (N + 15) / 16;            // 16 groups/block, 1 node/group
    const int ngrid3 = (2 * B + 15) / 16;       // layer-3 count <= 2B

    // one memset covers bcur + cnts + flag3 + flag2
    hipMemsetAsync(bcur, 0, ((size_t)512 + (size_t)4 * N) * sizeof(int), stream);

    k_flag3w<<<(B + 255) / 256, 256, 0, stream>>>(user, item, flag3, W, a, wa, B);
    k_part<<<dim3(pblk, 3), 256, 0, stream>>>(ei[0], ei[1], ei[2], bcur, edata, E, NBUC);
    k_bscan<<<1, 64, 0, stream>>>(bcur, boff, offs, N, E, NBUC);
    k_bucket2<<<dim3(NBUC, 3), 256, 0, stream>>>(edata, bcur, boff, flag3, flag2,
                                                 offs, dinv, perm, N, E, NBUC);
    k_lists<<<dim3(nblk, 3), 256, 0, stream>>>(flag2, flag3, list2, list3, cnts, N);

    // layer 1: full, fused across graphs
    k_gather1<<<dim3(ngrid, 3), 256, 0, stream>>>(emb, x, perm, offs, dinv,
                                                  l0, l1, l2, N, E);

    if (big) {
        // layers 2+3 fused across graphs, full grids
        k_gatherL<<<dim3(ngrid, 3), 256, 0, stream>>>(l0, l1, l2, list2, N, cnts, 1,
                                                      perm, offs, dinv,
                                                      t0, t1, t2, N, E, 0);
        k_gatherL<<<dim3(ngrid3, 3), 256, 0, stream>>>(t0, t1, t2, list3, 0, cnts + 3, 0,
                                                       perm, offs, dinv,
                                                       l0, l1, l2, N, E, 0);
    } else {
        for (int g = 0; g < 3; ++g) {
            k_gatherL<<<dim3(ngrid, 1), 256, 0, stream>>>(lbuf[g], lbuf[g], lbuf[g],
                                                          list2 + (size_t)g * N, 0,
                                                          cnts + g, 0,
                                                          perm, offs, dinv,
                                                          t0, t0, t0, N, E, g);
            k_gatherL<<<dim3(ngrid3, 1), 256, 0, stream>>>(t0, t0, t0, list3, 0,
                                                           cnts + 3, 0,
                                                           perm, offs, dinv,
                                                           lbuf[g], lbuf[g], lbuf[g],
                                                           N, E, g);
        }
    }

    k_score<<<(B + 3) / 4, 256, 0, stream>>>(user, item, l0, l1, l2, wa, out, B);
}